// Round 7
// baseline (116.512 us; speedup 1.0000x reference)
//
#include <hip/hip_runtime.h>
#include <cstdint>

// BFP quantize: block = channel vector at each (n,h,w), NCHW layout.
// N=64, C=256, H=W=56, mantissa_bits=3.
// delta = 2^(e-3), max_abs = m*2^e, m in [0.5,1) (frexp). q = trunc(x/delta)*delta.
// Exact pow2 arithmetic — absmax==0 verified R1/R2/R3b/R5/R6.
//
// R7: R1's structure (perfect counters: FETCH 1.000x, pass-B fully L3-hit,
// contiguous wave accesses) at 4x the wave count. One thread per scalar site:
// 200704 threads = 3136 waves = 12.25/CU, fully resident (784 blocks x 256),
// so R1's proven L3 residency carries over. No barriers / LDS / shuffles;
// ~30 VGPR -> 8 waves/SIMD allowed. Wave access = 64 x 4B = 256B contiguous
// (2 full lines); HW=3136 % 64 == 0 so waves never straddle images.
// R6 (full-line, 4-wave barrier groups) = 81.6us / 5.04 TB/s; this removes
// the barrier convoy and adds 2.7x latency-hiding margin.

constexpr int C   = 256;
constexpr int HW  = 56 * 56;     // 3136 (divisible by 64: waves stay in-image)
constexpr int CHW = C * HW;      // 802816

__device__ __forceinline__ int fexp(float x) {
    int e;
    (void)frexpf(x, &e);         // v_frexp_exp_i32_f32; e=0 for x==0
    return e;
}

__global__ __launch_bounds__(256, 8)
void bfp_kernel(const float* __restrict__ in, float* __restrict__ out, int total) {
    int t = blockIdx.x * 256 + threadIdx.x;
    if (t >= total) return;
    int n = t / HW;
    int r = t - n * HW;

    const float* p = in  + (size_t)n * CHW + r;
    float*       q = out + (size_t)n * CHW + r;

    // ---- pass A: abs-max over 256 channels, 4 accumulators, 8-deep batches ----
    float m0 = 0.f, m1 = 0.f, m2 = 0.f, m3 = 0.f;
#pragma unroll 2
    for (int c = 0; c < C; c += 8) {
        float a = p[(c + 0) * HW], b = p[(c + 1) * HW];
        float d = p[(c + 2) * HW], e = p[(c + 3) * HW];
        float f = p[(c + 4) * HW], g = p[(c + 5) * HW];
        float h = p[(c + 6) * HW], i = p[(c + 7) * HW];
        m0 = fmaxf(m0, fabsf(a)); m1 = fmaxf(m1, fabsf(b));
        m2 = fmaxf(m2, fabsf(d)); m3 = fmaxf(m3, fabsf(e));
        m0 = fmaxf(m0, fabsf(f)); m1 = fmaxf(m1, fabsf(g));
        m2 = fmaxf(m2, fabsf(h)); m3 = fmaxf(m3, fabsf(i));
    }
    float m = fmaxf(fmaxf(m0, m1), fmaxf(m2, m3));

    // ---- shared exponent -> delta = 2^(e-3), inv = 2^(3-e) (both exact) ----
    const int   e  = fexp(m);
    const float dq = ldexpf(1.f, e - 3);
    const float iq = ldexpf(1.f, 3 - e);

    // ---- pass B: re-read (L3-hit, proven R1), quantize, store ----
#pragma unroll 2
    for (int c = 0; c < C; c += 8) {
        float v[8];
#pragma unroll
        for (int k = 0; k < 8; ++k) v[k] = p[(c + k) * HW];
#pragma unroll
        for (int k = 0; k < 8; ++k) q[(c + k) * HW] = truncf(v[k] * iq) * dq;
    }
}

extern "C" void kernel_launch(void* const* d_in, const int* in_sizes, int n_in,
                              void* d_out, int out_size, void* d_ws, size_t ws_size,
                              hipStream_t stream) {
    const float* in = (const float*)d_in[0];
    float* out      = (float*)d_out;
    int total  = in_sizes[0] / C;          // 200704 spatial sites (N*HW)
    int blocks = (total + 255) / 256;      // 784 blocks, fully resident
    bfp_kernel<<<blocks, 256, 0, stream>>>(in, out, total);
}